// Round 10
// baseline (152.159 us; speedup 1.0000x reference)
//
#include <hip/hip_runtime.h>

#define BB 32
#define NP 2048
#define NG 2048
#define EPSF 1e-6f
#define BIGF 1e18f
#define FLTMAX 3.4e38f
#define MPP 8    // pred partials per row  (8 col-chunks of 256)
#define MPT 32   // tgt partials per col   (32 row-chunks of 64)

typedef float f32x4 __attribute__((ext_vector_type(4)));
typedef short s16x8 __attribute__((ext_vector_type(8)));

// ws layout (fully overwritten every call -> no init memsets):
//  [0, 8448)         : fpart[264][8] floats
//  [65536, +4MB)     : ppart u64 [b][C=8][row 2048]  (dist_bits<<32 | argmin col)
//  [65536+4MB, +8MB) : tpart f32 [b][R=32][col 2048]
#define FPART_OFF 0
#define PPART_OFF 65536
#define TPART_OFF (65536 + BB * MPP * NP * 8)

__device__ __forceinline__ unsigned short f2bf(float f) {  // round-to-nearest-even
  unsigned x = __float_as_uint(f);
  unsigned r = x + 0x7fffu + ((x >> 16) & 1u);
  return (unsigned short)(r >> 16);
}

// Shared-S MFMA kernel: each block computes one 64x256 tile of
//   S = pn + tn + BIG*(1-mask) - 2*P.T^T   (per batch)
// ONCE via mfma_f32_16x16x32_bf16 (K-slots: 0..2 coords / -2*coords,
// 3: 1*w3 where w3 = masked? BIG : tn, 4: pn*1), then reduces it BOTH ways:
// row-side masked min+argmin -> ppart, col-side min -> tpart (BIG in masked
// cols is killed by *mask in k_fin). Halves the pairwise work vs the dual
// VALU passes of R4-R9 and moves the dots to the matrix pipe.
// grid: 32 b * 32 R * 8 C = 8192 blocks; LB(256,8) -> 8 blocks/CU.
__global__ __launch_bounds__(256, 8) void k_dist(const float* __restrict__ preds,
                                                 const float* __restrict__ target,
                                                 const float* __restrict__ mask,
                                                 unsigned long long* __restrict__ ppart,
                                                 float* __restrict__ tpart) {
  __shared__ unsigned long long tS[256];  // per target: packed bf16 {-2x,-2y,-2z,w3}
  __shared__ float cmw[256][4];           // col-min per wave ([col][wave] for b128 read)
  const int bx = blockIdx.x;
  const int b = bx >> 8;
  const int R = (bx >> 3) & 31;
  const int C = bx & 7;
  const int tid = threadIdx.x;
  const int w = tid >> 6;
  const int l = tid & 63;
  const int lm = l & 15;   // MFMA: A row m / B col n / D col
  const int quad = l >> 4; // D rows = quad*4+r ; A/B k = quad*8+j
  const int c0 = C * 256;
  const int r0 = R * 64;

  // stage 256 targets for this col-chunk
  {
    const int n = c0 + tid;
    const float* tb = target + b * 4 * NG;
    float tx = tb[n], ty = tb[NG + n], tz = tb[2 * NG + n];
    float tn = fmaf(tx, tx, fmaf(ty, ty, tz * tz));
    float w3 = (mask[b * NG + n] == 0.0f) ? BIGF : tn;  // fold BIG mask into K-slot 3
    unsigned long long pk =
        (unsigned long long)f2bf(-2.0f * tx) |
        ((unsigned long long)f2bf(-2.0f * ty) << 16) |
        ((unsigned long long)f2bf(-2.0f * tz) << 32) |
        ((unsigned long long)f2bf(w3) << 48);
    tS[tid] = pk;
  }

  // A-frag (per wave, rows r0+16w+lm): {px,py,pz,1,pn,0,0,0} on quad0, else 0
  s16x8 afrag = {0, 0, 0, 0, 0, 0, 0, 0};
  {
    const int row = r0 + 16 * w + lm;
    const float* pb = preds + b * 5 * NP;
    float px = pb[row], py = pb[NP + row], pz = pb[2 * NP + row];
    float pn = fmaf(px, px, fmaf(py, py, pz * pz));
    if (quad == 0) {
      afrag[0] = (short)f2bf(px);
      afrag[1] = (short)f2bf(py);
      afrag[2] = (short)f2bf(pz);
      afrag[3] = (short)0x3f80;  // 1.0 bf16
      afrag[4] = (short)f2bf(pn);
    }
  }
  __syncthreads();

  float bv[4] = {FLTMAX, FLTMAX, FLTMAX, FLTMAX};
  int bi[4] = {0, 0, 0, 0};
  float cv[16];

#pragma unroll
  for (int t = 0; t < 16; t++) {
    unsigned long long pk = tS[t * 16 + lm];  // same addr across quads: broadcast
    s16x8 bfrag = {0, 0, 0, 0, 0, 0, 0, 0};
    if (quad == 0) {
      bfrag[0] = (short)(pk & 0xffffu);
      bfrag[1] = (short)((pk >> 16) & 0xffffu);
      bfrag[2] = (short)((pk >> 32) & 0xffffu);
      bfrag[3] = (short)(pk >> 48);
      bfrag[4] = (short)0x3f80;  // 1.0 pairs with A's pn slot
    }
    f32x4 acc = {0.0f, 0.0f, 0.0f, 0.0f};
    acc = __builtin_amdgcn_mfma_f32_16x16x32_bf16(afrag, bfrag, acc, 0, 0, 0);
    // acc[r] = S[row=quad*4+r][col=16t+lm] (masked dist, pre-clamp)
#pragma unroll
    for (int r = 0; r < 4; r++) {
      // cols increase with t; strict < keeps first index (jnp.argmin semantics)
      if (acc[r] < bv[r]) { bv[r] = acc[r]; bi[r] = t * 16 + lm; }
    }
    cv[t] = fminf(fminf(acc[0], acc[1]), fminf(acc[2], acc[3]));
  }

  // ---- row side: butterfly over the 16 lanes of this quad (idx tie-break) ----
#pragma unroll
  for (int off = 1; off < 16; off <<= 1) {
#pragma unroll
    for (int r = 0; r < 4; r++) {
      float ov = __shfl_xor(bv[r], off);
      int oi = __shfl_xor(bi[r], off);
      if (ov < bv[r] || (ov == bv[r] && oi < bi[r])) { bv[r] = ov; bi[r] = oi; }
    }
  }
  if (lm == 0) {
    unsigned long long* prow = &ppart[(b * MPP + C) * NP];
#pragma unroll
    for (int r = 0; r < 4; r++) {
      int grow = r0 + 16 * w + quad * 4 + r;
      float d = fmaxf(bv[r], 0.0f);  // ref clamps dist_sq at 0
      prow[grow] = ((unsigned long long)__float_as_uint(d) << 32) | (unsigned)(c0 + bi[r]);
    }
  }

  // ---- col side: reduce across quads, then across the 4 waves via LDS ----
#pragma unroll
  for (int t = 0; t < 16; t++) {
    float v = cv[t];
    v = fminf(v, __shfl_xor(v, 16));
    v = fminf(v, __shfl_xor(v, 32));
    cv[t] = v;
  }
  if (quad == 0) {
#pragma unroll
    for (int t = 0; t < 16; t++) cmw[t * 16 + lm][w] = cv[t];
  }
  __syncthreads();
  {
    float4 m4 = *(const float4*)cmw[tid];
    float cm = fminf(fminf(m4.x, m4.y), fminf(m4.z, m4.w));
    tpart[(b * MPT + R) * NG + c0 + tid] = fmaxf(cm, 0.0f);  // masked cols stay BIG; k_fin *mask kills them
  }
}

// Combine: blocks [0,128) pred side, [128,256) tgt side, [256,264) kld.
__global__ __launch_bounds__(256) void k_fin(const unsigned long long* __restrict__ ppart,
                                             const float* __restrict__ tpart,
                                             const float* __restrict__ preds,
                                             const float* __restrict__ target,
                                             const float* __restrict__ mask,
                                             const float* __restrict__ mu,
                                             const float* __restrict__ logvar,
                                             float* __restrict__ fpart) {
  __shared__ float red[4][8];
  const int bx = blockIdx.x;
  const int tid = threadIdx.x;
  const int wave = tid >> 6, lane = tid & 63;
  float q0 = 0.0f, q1 = 0.0f, q2 = 0.0f, q3 = 0.0f, q4 = 0.0f;

  if (bx < 128) {
    const int b = bx >> 2;
    const float* pb = preds + b * 5 * NP;
    const float* te = target + b * 4 * NG + 3 * NG;
#pragma unroll
    for (int e = 0; e < 2; e++) {
      int i = bx * 512 + e * 256 + tid;
      int n = i & 2047;
      unsigned long long best = 0xFFFFFFFFFFFFFFFFull;
      const unsigned long long* col = &ppart[b * MPP * NP + n];
#pragma unroll
      for (int mp = 0; mp < MPP; mp++) {
        unsigned long long v = col[mp * NP];  // coalesced across lanes
        best = v < best ? v : best;           // min packed: dist then index
      }
      float bd = __uint_as_float((unsigned)(best >> 32));
      int idx = (int)(best & 0xffffffffu);
      float mE = te[idx];
      float pE = pb[3 * NP + n];
      float ph = pb[4 * NP + n];
      q0 += bd;
      q1 += fabsf(pE - mE);
      q2 += ph * logf(ph + EPSF) + (1.0f - ph) * logf(1.0f - ph + EPSF);
      q3 += ph;
      q4 += pE * ph;
    }
  } else if (bx < 256) {
    const int bb = bx - 128;
    const int b = bb >> 2;
#pragma unroll
    for (int e = 0; e < 2; e++) {
      int i = bb * 512 + e * 256 + tid;
      int m = i & 2047;
      float d = FLTMAX;
      const float* col = &tpart[b * MPT * NG + m];
#pragma unroll
      for (int np_ = 0; np_ < MPT; np_++) d = fminf(d, col[np_ * NG]);
      float msk = mask[i];
      q0 += d * msk;  // masked cols carry BIG but msk==0 zeroes them
      q1 += msk;
      q2 += msk;
    }
  } else {
    const int bb = bx - 256;  // B*L = 8192 over 8 blocks
#pragma unroll
    for (int e = 0; e < 4; e++) {
      int i = bb * 1024 + e * 256 + tid;
      float m = mu[i], lv = logvar[i];
      q0 += 1.0f + lv - m * m - expf(lv);
    }
  }

  float qs[5] = {q0, q1, q2, q3, q4};
  for (int k = 0; k < 5; k++) {
    float v = qs[k];
    v += __shfl_down(v, 32);
    v += __shfl_down(v, 16);
    v += __shfl_down(v, 8);
    v += __shfl_down(v, 4);
    v += __shfl_down(v, 2);
    v += __shfl_down(v, 1);
    if (lane == 0) red[wave][k] = v;
  }
  __syncthreads();
  if (tid < 5) fpart[bx * 8 + tid] = red[0][tid] + red[1][tid] + red[2][tid] + red[3][tid];
}

// Single-block final reduction over fpart rows + loss assembly.
__global__ __launch_bounds__(256) void k_final(const float* __restrict__ fpart,
                                               const float* __restrict__ e_init,
                                               const float* __restrict__ kl_weight,
                                               float* __restrict__ out) {
  __shared__ float red[4][8];
  const int t = threadIdx.x;
  const int wave = t >> 6, lane = t & 63;
  float g[8] = {0, 0, 0, 0, 0, 0, 0, 0};
  if (t < 128) {
    const float* r = &fpart[t * 8];
    g[0] = r[0]; g[1] = r[1]; g[2] = r[2];
    const float* r2 = &fpart[(128 + t) * 8];
    g[3] = r2[0]; g[4] = r2[1];
  }
  if (t < 8) g[5] = fpart[(256 + t) * 8];
  if (t < BB) {
    float hit = 0.0f, eh = 0.0f, mk = 0.0f;
#pragma unroll
    for (int k = 0; k < 4; k++) {
      hit += fpart[(4 * t + k) * 8 + 3];
      eh += fpart[(4 * t + k) * 8 + 4];
      mk += fpart[(128 + 4 * t + k) * 8 + 2];
    }
    float dh = hit - mk;
    g[6] = dh * dh;
    float de = eh - e_init[t];
    g[7] = de * de;
  }
  for (int k = 0; k < 8; k++) {
    float v = g[k];
    v += __shfl_down(v, 32);
    v += __shfl_down(v, 16);
    v += __shfl_down(v, 8);
    v += __shfl_down(v, 4);
    v += __shfl_down(v, 2);
    v += __shfl_down(v, 1);
    if (lane == 0) red[wave][k] = v;
  }
  __syncthreads();
  if (t == 0) {
    float s[8];
    for (int k = 0; k < 8; k++) s[k] = red[0][k] + red[1][k] + red[2][k] + red[3][k];
    const float invBN = 1.0f / (float)(BB * NP);
    float chamfer_pred = s[0] * invBN;
    float localE = s[1] * invBN;
    float ent = -s[2] * invBN;
    float chamfer_tgt = s[3] / s[4];
    float kld = -0.5f * s[5] / (float)BB;
    float hit = s[6] / (float)BB;
    float ge = s[7] / (float)BB;

    float loss_chamf = (chamfer_tgt + chamfer_pred) * 0.001f;  // LAMBDA_CHAMFER
    float losskld = kl_weight[0] * kld;
    float loss_ge = 10.0f * ge;    // LAMBDA_E_SUM
    float loss_hit = 20.0f * hit;  // LAMBDA_HIT
    float loss_ent = 0.1f * ent;   // LAMBDA_HIT_ENTROPY

    float total = loss_chamf + localE + losskld + loss_ge + loss_hit + loss_ent;
    out[0] = total;
    out[1] = loss_chamf;
    out[2] = localE;
    out[3] = loss_ge;
    out[4] = loss_hit;
    out[5] = losskld;
  }
}

extern "C" void kernel_launch(void* const* d_in, const int* in_sizes, int n_in,
                              void* d_out, int out_size, void* d_ws, size_t ws_size,
                              hipStream_t stream) {
  const float* preds = (const float*)d_in[0];
  const float* target = (const float*)d_in[1];
  const float* mask = (const float*)d_in[2];
  const float* mu = (const float*)d_in[3];
  const float* logvar = (const float*)d_in[4];
  const float* e_init = (const float*)d_in[5];
  const float* kl_weight = (const float*)d_in[6];
  float* fpart = (float*)((char*)d_ws + FPART_OFF);
  unsigned long long* ppart = (unsigned long long*)((char*)d_ws + PPART_OFF);
  float* tpart = (float*)((char*)d_ws + TPART_OFF);
  float* out = (float*)d_out;

  k_dist<<<BB * 32 * 8, 256, 0, stream>>>(preds, target, mask, ppart, tpart);
  k_fin<<<264, 256, 0, stream>>>(ppart, tpart, preds, target, mask, mu, logvar, fpart);
  k_final<<<1, 256, 0, stream>>>(fpart, e_init, kl_weight, out);
}

// Round 11
// 116.713 us; speedup vs baseline: 1.3037x; 1.3037x over previous
//
#include <hip/hip_runtime.h>

#define BB 32
#define NP 2048
#define NG 2048
#define EPSF 1e-6f
#define BIGF 1e18f
#define FLTMAX 3.4e38f
#define MPP 8    // pred partials per row  (8 col-chunks of 256)
#define MPT 32   // tgt partials per col   (32 row-chunks of 64)

typedef float f32x4 __attribute__((ext_vector_type(4)));
typedef short s16x8 __attribute__((ext_vector_type(8)));

// ws layout (fully overwritten every call -> no init memsets):
//  [0, 8448)         : fpart[264][8] floats
//  [65536, +4MB)     : ppart u64 [b][C=8][row 2048]  (dist_bits<<32 | argmin col)
//  [65536+4MB, +8MB) : tpart f32 [b][R=32][col 2048]
#define FPART_OFF 0
#define PPART_OFF 65536
#define TPART_OFF (65536 + BB * MPP * NP * 8)

__device__ __forceinline__ unsigned short f2bf(float f) {  // round-to-nearest-even
  unsigned x = __float_as_uint(f);
  unsigned r = x + 0x7fffu + ((x >> 16) & 1u);
  return (unsigned short)(r >> 16);
}

// Shared-S MFMA kernel: each block computes one 64x256 tile of
//   S = pn + tn + BIG*(1-mask) - 2*P.T^T   (per batch)
// ONCE via mfma_f32_16x16x32_bf16 (K slots 0-2: coords vs -2*coords,
// 3: 1*w3 with w3 = masked? BIG : tn, 4: pn*1), reduced BOTH ways.
// R10 lesson: LB(256,8) caps the unified VGPR file at 64 -> the live state
// (cv[16]+bv/bi+frags) spilled to scratch, 150MB of HBM round-trip.
// LB(256,4) gives 128 VGPRs -> no spill; 4 waves/SIMD + 32 queued blocks/CU.
// grid: 32 b * 32 R * 8 C = 8192 blocks.
__global__ __launch_bounds__(256, 4) void k_dist(const float* __restrict__ preds,
                                                 const float* __restrict__ target,
                                                 const float* __restrict__ mask,
                                                 unsigned long long* __restrict__ ppart,
                                                 float* __restrict__ tpart) {
  __shared__ unsigned long long tS[256];  // per target: packed bf16 {-2x,-2y,-2z,w3}
  __shared__ float cmw[4][256];           // col-min per wave; [w][col] -> stride-1 reads
  const int bx = blockIdx.x;
  const int b = bx >> 8;
  const int R = (bx >> 3) & 31;
  const int C = bx & 7;
  const int tid = threadIdx.x;
  const int w = tid >> 6;
  const int l = tid & 63;
  const int lm = l & 15;   // MFMA: A row m / B col n / D col
  const int quad = l >> 4; // D rows = quad*4+r ; A/B k = quad*8+j
  const int c0 = C * 256;
  const int r0 = R * 64;

  // stage 256 targets for this col-chunk
  {
    const int n = c0 + tid;
    const float* tb = target + b * 4 * NG;
    float tx = tb[n], ty = tb[NG + n], tz = tb[2 * NG + n];
    float tn = fmaf(tx, tx, fmaf(ty, ty, tz * tz));
    float w3 = (mask[b * NG + n] == 0.0f) ? BIGF : tn;  // fold BIG mask into K-slot 3
    unsigned long long pk =
        (unsigned long long)f2bf(-2.0f * tx) |
        ((unsigned long long)f2bf(-2.0f * ty) << 16) |
        ((unsigned long long)f2bf(-2.0f * tz) << 32) |
        ((unsigned long long)f2bf(w3) << 48);
    tS[tid] = pk;
  }

  // A-frag (per wave, rows r0+16w+lm): {px,py,pz,1,pn,0,0,0} on quad0, else 0.
  // Quads 1-3 zeroed here => B never needs zeroing (0 * anything = 0).
  s16x8 afrag = {0, 0, 0, 0, 0, 0, 0, 0};
  {
    const int row = r0 + 16 * w + lm;
    const float* pb = preds + b * 5 * NP;
    float px = pb[row], py = pb[NP + row], pz = pb[2 * NP + row];
    float pn = fmaf(px, px, fmaf(py, py, pz * pz));
    if (quad == 0) {
      afrag[0] = (short)f2bf(px);
      afrag[1] = (short)f2bf(py);
      afrag[2] = (short)f2bf(pz);
      afrag[3] = (short)0x3f80;  // 1.0 bf16
      afrag[4] = (short)f2bf(pn);
    }
  }
  __syncthreads();

  float bv[4] = {FLTMAX, FLTMAX, FLTMAX, FLTMAX};
  int bi[4] = {0, 0, 0, 0};
  float cv[16];

#pragma unroll
  for (int t = 0; t < 16; t++) {
    unsigned long long pk = tS[t * 16 + lm];  // same addr across quads: broadcast
    union { unsigned long long u; short s[4]; } cvt;
    cvt.u = pk;
    s16x8 bfrag;
    bfrag[0] = cvt.s[0];
    bfrag[1] = cvt.s[1];
    bfrag[2] = cvt.s[2];
    bfrag[3] = cvt.s[3];
    bfrag[4] = (short)0x3f80;  // 1.0 pairs with A's pn slot
    bfrag[5] = 0; bfrag[6] = 0; bfrag[7] = 0;
    f32x4 acc = {0.0f, 0.0f, 0.0f, 0.0f};
    acc = __builtin_amdgcn_mfma_f32_16x16x32_bf16(afrag, bfrag, acc, 0, 0, 0);
    // acc[r] = S[row=quad*4+r][col=16t+lm] (masked dist, pre-clamp)
#pragma unroll
    for (int r = 0; r < 4; r++) {
      // cols increase with t; strict < keeps first index (jnp.argmin semantics)
      if (acc[r] < bv[r]) { bv[r] = acc[r]; bi[r] = t * 16 + lm; }
    }
    cv[t] = fminf(fminf(acc[0], acc[1]), fminf(acc[2], acc[3]));
  }

  // ---- row side: butterfly over the 16 lanes of this quad (idx tie-break) ----
#pragma unroll
  for (int off = 1; off < 16; off <<= 1) {
#pragma unroll
    for (int r = 0; r < 4; r++) {
      float ov = __shfl_xor(bv[r], off);
      int oi = __shfl_xor(bi[r], off);
      if (ov < bv[r] || (ov == bv[r] && oi < bi[r])) { bv[r] = ov; bi[r] = oi; }
    }
  }
  if (lm == 0) {
    unsigned long long* prow = &ppart[(b * MPP + C) * NP];
#pragma unroll
    for (int r = 0; r < 4; r++) {
      int grow = r0 + 16 * w + quad * 4 + r;
      float d = fmaxf(bv[r], 0.0f);  // ref clamps dist_sq at 0
      prow[grow] = ((unsigned long long)__float_as_uint(d) << 32) | (unsigned)(c0 + bi[r]);
    }
  }

  // ---- col side: reduce across quads, stage per wave (conflict-free banks) ----
#pragma unroll
  for (int t = 0; t < 16; t++) {
    float v = cv[t];
    v = fminf(v, __shfl_xor(v, 16));
    v = fminf(v, __shfl_xor(v, 32));
    if (quad == 0) cmw[w][t * 16 + lm] = v;  // 16 lanes -> 16 distinct banks
  }
  __syncthreads();
  {
    float cm = fminf(fminf(cmw[0][tid], cmw[1][tid]),
                     fminf(cmw[2][tid], cmw[3][tid]));  // stride-1 b32 reads
    tpart[(b * MPT + R) * NG + c0 + tid] = fmaxf(cm, 0.0f);  // BIG cols killed by *mask in k_fin
  }
}

// Combine: blocks [0,128) pred side, [128,256) tgt side, [256,264) kld.
__global__ __launch_bounds__(256) void k_fin(const unsigned long long* __restrict__ ppart,
                                             const float* __restrict__ tpart,
                                             const float* __restrict__ preds,
                                             const float* __restrict__ target,
                                             const float* __restrict__ mask,
                                             const float* __restrict__ mu,
                                             const float* __restrict__ logvar,
                                             float* __restrict__ fpart) {
  __shared__ float red[4][8];
  const int bx = blockIdx.x;
  const int tid = threadIdx.x;
  const int wave = tid >> 6, lane = tid & 63;
  float q0 = 0.0f, q1 = 0.0f, q2 = 0.0f, q3 = 0.0f, q4 = 0.0f;

  if (bx < 128) {
    const int b = bx >> 2;
    const float* pb = preds + b * 5 * NP;
    const float* te = target + b * 4 * NG + 3 * NG;
#pragma unroll
    for (int e = 0; e < 2; e++) {
      int i = bx * 512 + e * 256 + tid;
      int n = i & 2047;
      unsigned long long best = 0xFFFFFFFFFFFFFFFFull;
      const unsigned long long* col = &ppart[b * MPP * NP + n];
#pragma unroll
      for (int mp = 0; mp < MPP; mp++) {
        unsigned long long v = col[mp * NP];  // coalesced across lanes
        best = v < best ? v : best;           // min packed: dist then index
      }
      float bd = __uint_as_float((unsigned)(best >> 32));
      int idx = (int)(best & 0xffffffffu);
      float mE = te[idx];
      float pE = pb[3 * NP + n];
      float ph = pb[4 * NP + n];
      q0 += bd;
      q1 += fabsf(pE - mE);
      q2 += ph * logf(ph + EPSF) + (1.0f - ph) * logf(1.0f - ph + EPSF);
      q3 += ph;
      q4 += pE * ph;
    }
  } else if (bx < 256) {
    const int bb = bx - 128;
    const int b = bb >> 2;
#pragma unroll
    for (int e = 0; e < 2; e++) {
      int i = bb * 512 + e * 256 + tid;
      int m = i & 2047;
      float d = FLTMAX;
      const float* col = &tpart[b * MPT * NG + m];
#pragma unroll
      for (int np_ = 0; np_ < MPT; np_++) d = fminf(d, col[np_ * NG]);
      float msk = mask[i];
      q0 += d * msk;  // masked cols carry BIG but msk==0 zeroes them
      q1 += msk;
      q2 += msk;
    }
  } else {
    const int bb = bx - 256;  // B*L = 8192 over 8 blocks
#pragma unroll
    for (int e = 0; e < 4; e++) {
      int i = bb * 1024 + e * 256 + tid;
      float m = mu[i], lv = logvar[i];
      q0 += 1.0f + lv - m * m - expf(lv);
    }
  }

  float qs[5] = {q0, q1, q2, q3, q4};
  for (int k = 0; k < 5; k++) {
    float v = qs[k];
    v += __shfl_down(v, 32);
    v += __shfl_down(v, 16);
    v += __shfl_down(v, 8);
    v += __shfl_down(v, 4);
    v += __shfl_down(v, 2);
    v += __shfl_down(v, 1);
    if (lane == 0) red[wave][k] = v;
  }
  __syncthreads();
  if (tid < 5) fpart[bx * 8 + tid] = red[0][tid] + red[1][tid] + red[2][tid] + red[3][tid];
}

// Single-block final reduction over fpart rows + loss assembly.
__global__ __launch_bounds__(256) void k_final(const float* __restrict__ fpart,
                                               const float* __restrict__ e_init,
                                               const float* __restrict__ kl_weight,
                                               float* __restrict__ out) {
  __shared__ float red[4][8];
  const int t = threadIdx.x;
  const int wave = t >> 6, lane = t & 63;
  float g[8] = {0, 0, 0, 0, 0, 0, 0, 0};
  if (t < 128) {
    const float* r = &fpart[t * 8];
    g[0] = r[0]; g[1] = r[1]; g[2] = r[2];
    const float* r2 = &fpart[(128 + t) * 8];
    g[3] = r2[0]; g[4] = r2[1];
  }
  if (t < 8) g[5] = fpart[(256 + t) * 8];
  if (t < BB) {
    float hit = 0.0f, eh = 0.0f, mk = 0.0f;
#pragma unroll
    for (int k = 0; k < 4; k++) {
      hit += fpart[(4 * t + k) * 8 + 3];
      eh += fpart[(4 * t + k) * 8 + 4];
      mk += fpart[(128 + 4 * t + k) * 8 + 2];
    }
    float dh = hit - mk;
    g[6] = dh * dh;
    float de = eh - e_init[t];
    g[7] = de * de;
  }
  for (int k = 0; k < 8; k++) {
    float v = g[k];
    v += __shfl_down(v, 32);
    v += __shfl_down(v, 16);
    v += __shfl_down(v, 8);
    v += __shfl_down(v, 4);
    v += __shfl_down(v, 2);
    v += __shfl_down(v, 1);
    if (lane == 0) red[wave][k] = v;
  }
  __syncthreads();
  if (t == 0) {
    float s[8];
    for (int k = 0; k < 8; k++) s[k] = red[0][k] + red[1][k] + red[2][k] + red[3][k];
    const float invBN = 1.0f / (float)(BB * NP);
    float chamfer_pred = s[0] * invBN;
    float localE = s[1] * invBN;
    float ent = -s[2] * invBN;
    float chamfer_tgt = s[3] / s[4];
    float kld = -0.5f * s[5] / (float)BB;
    float hit = s[6] / (float)BB;
    float ge = s[7] / (float)BB;

    float loss_chamf = (chamfer_tgt + chamfer_pred) * 0.001f;  // LAMBDA_CHAMFER
    float losskld = kl_weight[0] * kld;
    float loss_ge = 10.0f * ge;    // LAMBDA_E_SUM
    float loss_hit = 20.0f * hit;  // LAMBDA_HIT
    float loss_ent = 0.1f * ent;   // LAMBDA_HIT_ENTROPY

    float total = loss_chamf + localE + losskld + loss_ge + loss_hit + loss_ent;
    out[0] = total;
    out[1] = loss_chamf;
    out[2] = localE;
    out[3] = loss_ge;
    out[4] = loss_hit;
    out[5] = losskld;
  }
}

extern "C" void kernel_launch(void* const* d_in, const int* in_sizes, int n_in,
                              void* d_out, int out_size, void* d_ws, size_t ws_size,
                              hipStream_t stream) {
  const float* preds = (const float*)d_in[0];
  const float* target = (const float*)d_in[1];
  const float* mask = (const float*)d_in[2];
  const float* mu = (const float*)d_in[3];
  const float* logvar = (const float*)d_in[4];
  const float* e_init = (const float*)d_in[5];
  const float* kl_weight = (const float*)d_in[6];
  float* fpart = (float*)((char*)d_ws + FPART_OFF);
  unsigned long long* ppart = (unsigned long long*)((char*)d_ws + PPART_OFF);
  float* tpart = (float*)((char*)d_ws + TPART_OFF);
  float* out = (float*)d_out;

  k_dist<<<BB * 32 * 8, 256, 0, stream>>>(preds, target, mask, ppart, tpart);
  k_fin<<<264, 256, 0, stream>>>(ppart, tpart, preds, target, mask, mu, logvar, fpart);
  k_final<<<1, 256, 0, stream>>>(fpart, e_init, kl_weight, out);
}